// Round 6
// baseline (153.357 us; speedup 1.0000x reference)
//
#include <hip/hip_runtime.h>
#include <hip/hip_bf16.h>

// attention_11269994185437: B=4, C=256, CQK=32, H=W=64 -> N=4096
// out = gamma * (V @ P) + x,  P[n,m] = softmax over m of S[n,m], S = Q^T K.
// Qt pre-scaled by L2E: S' = L2E*S. cbias[b][n] = -max(S') - log2(sum exp2(S'-max)).
// k_attn_out computes out^T = E^T * V^T, software-pipelined:
//   iter t: load Q(t+2),V(t+1),cb(t+1) | S(t+1) MFMA | E(t) VALU | PV(t) MFMA
//   (register double-buffer, manual unroll-2, all indices compile-time)
// k_comb: sum partials, LDS-transpose [m][c]->[c][m], out = g*sum + x.

#define NB 4
#define CC 256
#define NN 4096
#define MSPLIT 4
#define L2E 1.44269504088896340f

typedef short  short4v  __attribute__((ext_vector_type(4)));
typedef short  short8v  __attribute__((ext_vector_type(8)));
typedef __bf16 bf16x8   __attribute__((ext_vector_type(8)));
typedef float  f32x4    __attribute__((ext_vector_type(4)));
typedef float  f32x16   __attribute__((ext_vector_type(16)));

static __device__ __forceinline__ unsigned short f2bf(float f) {
  union { __bf16 h; unsigned short u; } v; v.h = (__bf16)f; return v.u;
}

union FragU { short8v s; bf16x8 b; unsigned u[4]; };
union PackU { __bf16 h[8]; unsigned u[4]; };

static __device__ __forceinline__ bf16x8 ld_frag(const unsigned short* p) {
  FragU u; u.s = *(const short8v*)p; return u.b;
}

static __device__ __forceinline__ f32x16 zero16() {
  f32x16 v;
#pragma unroll
  for (int i = 0; i < 16; ++i) v[i] = 0.0f;
  return v;
}

static __device__ __forceinline__ f32x16 mfma32(bf16x8 a, bf16x8 b, f32x16 c) {
  return __builtin_amdgcn_mfma_f32_32x32x16_bf16(a, b, c, 0, 0, 0);
}

// ---------------- Kernel 1: QKV projection --------------------------------
__global__ __launch_bounds__(256) void k_proj(
    const float* __restrict__ x,
    const float* __restrict__ Wq, const float* __restrict__ bq,
    const float* __restrict__ Wk, const float* __restrict__ bk,
    const float* __restrict__ Wv, const float* __restrict__ bv,
    unsigned short* __restrict__ Qt, unsigned short* __restrict__ Kt,
    unsigned short* __restrict__ Vt)
{
  __shared__ unsigned short xs[32][268];   // xs[n_local][c]
  const int t = threadIdx.x;
  const int b = blockIdx.y;
  const int n0 = blockIdx.x * 32;
  const int w = t >> 6, l = t & 63, h = l >> 5, col = l & 31;

  const float* xb = x + (size_t)b * CC * NN;
  {
    const int c_off = t >> 3, nl = 4 * (t & 7);
#pragma unroll
    for (int c0 = 0; c0 < CC; c0 += 32) {
      int c = c0 + c_off;
      f32x4 v4 = *(const f32x4*)(xb + (size_t)c * NN + n0 + nl);
#pragma unroll
      for (int j = 0; j < 4; ++j) xs[nl + j][c] = f2bf(v4[j]);
    }
  }
  __syncthreads();

  for (int f = w; f < 10; f += 4) {
    const float* Wsrc; const float* bsrc; int rowbase; int mode;
    if (f == 0)      { Wsrc = Wq; bsrc = bq; rowbase = 0;            mode = 0; }
    else if (f == 1) { Wsrc = Wk; bsrc = bk; rowbase = 0;            mode = 1; }
    else             { Wsrc = Wv; bsrc = bv; rowbase = (f - 2) * 32; mode = 2; }

    f32x16 acc0 = zero16();
    const float* wr = Wsrc + (size_t)(rowbase + col) * CC + 8 * h;

#pragma unroll
    for (int k0 = 0; k0 < CC; k0 += 16) {
      f32x4 w0 = *(const f32x4*)(wr + k0);
      f32x4 w1 = *(const f32x4*)(wr + k0 + 4);
      FragU a;
#pragma unroll
      for (int j = 0; j < 4; ++j) { a.s[j] = (short)f2bf(w0[j]); a.s[4 + j] = (short)f2bf(w1[j]); }
      const unsigned short* p0 = &xs[col][k0 + 8 * h];
      FragU b0;
      short4v t0a = *(const short4v*)p0, t0b = *(const short4v*)(p0 + 4);
#pragma unroll
      for (int j = 0; j < 4; ++j) { b0.s[j] = t0a[j]; b0.s[4 + j] = t0b[j]; }
      acc0 = mfma32(a.b, b0.b, acc0);
    }

    const int n = n0 + col;
#pragma unroll
    for (int q = 0; q < 4; ++q) {
      f32x4 bias4 = *(const f32x4*)(bsrc + rowbase + 8 * q + 4 * h);
      float vals[4];
#pragma unroll
      for (int i = 0; i < 4; ++i) vals[i] = acc0[4 * q + i] + bias4[i];
      if (mode == 2) {
        // Vt[b][n>>4][c][n&15]
        const size_t tb = ((size_t)b * (NN >> 4) + (n >> 4)) * CC * 16 + (n & 15);
#pragma unroll
        for (int i = 0; i < 4; ++i) {
          int c = rowbase + 8 * q + 4 * h + i;
          Vt[tb + (size_t)c * 16] = f2bf(vals[i]);
        }
      } else {
        unsigned short* dst = (mode == 0) ? Qt : Kt;
        const float scale = (mode == 0) ? L2E : 1.0f;   // fold L2E into Q
        short4v s4;
#pragma unroll
        for (int i = 0; i < 4; ++i) s4[i] = (short)f2bf(vals[i] * scale);
        *(short4v*)(dst + ((size_t)b * NN + n) * 32 + 8 * q + 4 * h) = s4;
      }
    }
  }
}

// ---------------- Kernel 2a: partial row stats (single sweep) -------------
// grid (N/32, B, MSPLIT), block 256 (wave w covers 256 m). All 8 S-tiles
// held in registers: K loaded once, one MFMA pass, then max+sum from regs.
__global__ __launch_bounds__(256) void k_rowstats_part(
    const unsigned short* __restrict__ Qt, const unsigned short* __restrict__ Kt,
    float* __restrict__ pmax, float* __restrict__ psum)
{
  __shared__ float smax[4][32], ssum[4][32];
  const int t = threadIdx.x;
  const int w = t >> 6, l = t & 63, h = l >> 5, col = l & 31;
  const int b = blockIdx.y;
  const int n0 = blockIdx.x * 32;
  const int mlen = NN / MSPLIT / 4;                 // 256
  const int mbase = blockIdx.z * (NN / MSPLIT) + w * mlen;
  const unsigned short* Qb = Qt + (size_t)b * NN * 32;
  const unsigned short* Kb = Kt + (size_t)b * NN * 32;

  bf16x8 aq0 = ld_frag(Qb + (size_t)(n0 + col) * 32 + 8 * h);
  bf16x8 aq1 = ld_frag(Qb + (size_t)(n0 + col) * 32 + 16 + 8 * h);

  f32x16 St[8];
#pragma unroll
  for (int mt = 0; mt < 8; ++mt) {
    const int m0 = mbase + mt * 32;
    bf16x8 bk0 = ld_frag(Kb + (size_t)(m0 + col) * 32 + 8 * h);
    bf16x8 bk1 = ld_frag(Kb + (size_t)(m0 + col) * 32 + 16 + 8 * h);
    f32x16 S = zero16();
    S = mfma32(aq0, bk0, S);
    St[mt] = mfma32(aq1, bk1, S);
  }

  float mx[16];
#pragma unroll
  for (int r = 0; r < 16; ++r) mx[r] = -3.4e38f;
#pragma unroll
  for (int mt = 0; mt < 8; ++mt)
#pragma unroll
    for (int r = 0; r < 16; ++r) mx[r] = fmaxf(mx[r], St[mt][r]);
#pragma unroll
  for (int off = 1; off < 32; off <<= 1)
#pragma unroll
    for (int r = 0; r < 16; ++r) mx[r] = fmaxf(mx[r], __shfl_xor(mx[r], off));

  float sm[16];
#pragma unroll
  for (int r = 0; r < 16; ++r) sm[r] = 0.0f;
#pragma unroll
  for (int mt = 0; mt < 8; ++mt)
#pragma unroll
    for (int r = 0; r < 16; ++r) sm[r] += __builtin_amdgcn_exp2f(St[mt][r] - mx[r]);
#pragma unroll
  for (int off = 1; off < 32; off <<= 1)
#pragma unroll
    for (int r = 0; r < 16; ++r) sm[r] += __shfl_xor(sm[r], off);

  if (col == 0) {
#pragma unroll
    for (int r = 0; r < 16; ++r) {
      int nl = (r & 3) + 8 * (r >> 2) + 4 * h;
      smax[w][nl] = mx[r];
      ssum[w][nl] = sm[r];
    }
  }
  __syncthreads();

  if (t < 32) {
    float gm = smax[0][t];
#pragma unroll
    for (int wv = 1; wv < 4; ++wv) gm = fmaxf(gm, smax[wv][t]);
    float s = 0.0f;
#pragma unroll
    for (int wv = 0; wv < 4; ++wv)
      s += ssum[wv][t] * __builtin_amdgcn_exp2f(smax[wv][t] - gm);
    const size_t base = ((size_t)b * MSPLIT + blockIdx.z) * NN;
    pmax[base + n0 + t] = gm;
    psum[base + n0 + t] = s;
  }
}

// ---------------- Kernel 2b: combine -> cbias = -max' - log2(sum) ---------
__global__ __launch_bounds__(256) void k_statfin(
    const float* __restrict__ pmax, const float* __restrict__ psum,
    float* __restrict__ cbias)
{
  const int i = blockIdx.x * 256 + threadIdx.x;
  const int b = i >> 12, n = i & (NN - 1);
  float pm[MSPLIT], ps[MSPLIT];
#pragma unroll
  for (int s = 0; s < MSPLIT; ++s) {
    pm[s] = pmax[((size_t)b * MSPLIT + s) * NN + n];
    ps[s] = psum[((size_t)b * MSPLIT + s) * NN + n];
  }
  float gmax = pm[0];
#pragma unroll
  for (int s = 1; s < MSPLIT; ++s) gmax = fmaxf(gmax, pm[s]);
  float gsum = 0.0f;
#pragma unroll
  for (int s = 0; s < MSPLIT; ++s) gsum += ps[s] * __builtin_amdgcn_exp2f(pm[s] - gmax);
  cbias[i] = -gmax - __builtin_amdgcn_logf(gsum);
}

// ---------------- Kernel 3: out^T = E^T * V^T (pipelined) -----------------
// Body for tile t: loads Q(t+2)->aqN, V(t+1)->Vn, cb(t+1)->cbn;
// computes Snew = S(t+1) from aqB (already in regs); E(t) from Scur+cbc;
// PV(t) from Vc. All buffer indices compile-time (manual unroll-2 swap).
#define PV_BODY(T, Scur, Snew, aqB0, aqB1, aqN0, aqN1, Vc, Vn, cbc, cbn)      \
  {                                                                            \
    const int t_ = (T);                                                        \
    const int t2_ = (t_ + 2 < iters) ? t_ + 2 : t_ + 2 - iters;                \
    const int t1_ = (t_ + 1 < iters) ? t_ + 1 : 0;                             \
    const int nn2_ = nbeg + (t2_ << 5);                                        \
    const int nn1_ = nbeg + (t1_ << 5);                                        \
    aqN0 = ld_frag(Qb + (size_t)(nn2_ + col) * 32 + 8 * h);                    \
    aqN1 = ld_frag(Qb + (size_t)(nn2_ + col) * 32 + 16 + 8 * h);               \
    {                                                                          \
      const unsigned short* vt0_ =                                             \
          Vtb + (((size_t)(nn1_ >> 4)) * CC + cbase + col) * 16 + 8 * h;       \
      const unsigned short* vt1_ = vt0_ + (size_t)CC * 16;                     \
      Vn[0] = ld_frag(vt0_);                                                   \
      Vn[1] = ld_frag(vt0_ + 32 * 16);                                         \
      Vn[2] = ld_frag(vt0_ + 64 * 16);                                         \
      Vn[3] = ld_frag(vt0_ + 96 * 16);                                         \
      Vn[4] = ld_frag(vt1_);                                                   \
      Vn[5] = ld_frag(vt1_ + 32 * 16);                                         \
      Vn[6] = ld_frag(vt1_ + 64 * 16);                                         \
      Vn[7] = ld_frag(vt1_ + 96 * 16);                                         \
    }                                                                          \
    _Pragma("unroll")                                                          \
    for (int q_ = 0; q_ < 4; ++q_)                                             \
      cbn[q_] = *(const f32x4*)(cb + nn1_ + 8 * q_ + 4 * h);                   \
    Snew = zero16();                                                           \
    Snew = mfma32(aqB0, bk0, Snew);                                            \
    Snew = mfma32(aqB1, bk1, Snew);                                            \
    PackU p0_, p1_;                                                            \
    _Pragma("unroll")                                                          \
    for (int q_ = 0; q_ < 4; ++q_) {                                           \
      _Pragma("unroll")                                                        \
      for (int i_ = 0; i_ < 4; ++i_) {                                         \
        float e_ = __builtin_amdgcn_exp2f(Scur[4 * q_ + i_] + cbc[q_][i_]);    \
        if (q_ < 2) p0_.h[4 * q_ + i_] = (__bf16)e_;                           \
        else        p1_.h[4 * (q_ - 2) + i_] = (__bf16)e_;                     \
      }                                                                        \
    }                                                                          \
    unsigned e00_ = p0_.u[0], e02_ = p0_.u[2];                                 \
    unsigned e01_ = p0_.u[1], e03_ = p0_.u[3];                                 \
    unsigned e10_ = p1_.u[0], e12_ = p1_.u[2];                                 \
    unsigned e11_ = p1_.u[1], e13_ = p1_.u[3];                                 \
    asm("v_permlane32_swap_b32 %0, %1" : "+v"(e00_), "+v"(e02_));              \
    asm("v_permlane32_swap_b32 %0, %1" : "+v"(e01_), "+v"(e03_));              \
    asm("v_permlane32_swap_b32 %0, %1" : "+v"(e10_), "+v"(e12_));              \
    asm("v_permlane32_swap_b32 %0, %1" : "+v"(e11_), "+v"(e13_));              \
    FragU be0_, be1_;                                                          \
    be0_.u[0] = e00_; be0_.u[1] = e01_; be0_.u[2] = e02_; be0_.u[3] = e03_;    \
    be1_.u[0] = e10_; be1_.u[1] = e11_; be1_.u[2] = e12_; be1_.u[3] = e13_;    \
    acc[0] = mfma32(be0_.b, Vc[0], acc[0]);                                    \
    acc[0] = mfma32(be1_.b, Vc[4], acc[0]);                                    \
    acc[1] = mfma32(be0_.b, Vc[1], acc[1]);                                    \
    acc[1] = mfma32(be1_.b, Vc[5], acc[1]);                                    \
    acc[2] = mfma32(be0_.b, Vc[2], acc[2]);                                    \
    acc[2] = mfma32(be1_.b, Vc[6], acc[2]);                                    \
    acc[3] = mfma32(be0_.b, Vc[3], acc[3]);                                    \
    acc[3] = mfma32(be1_.b, Vc[7], acc[3]);                                    \
  }

__global__ __launch_bounds__(256) void k_attn_out(
    const unsigned short* __restrict__ Qt, const unsigned short* __restrict__ Kt,
    const unsigned short* __restrict__ Vt,
    const float* __restrict__ cbias,
    float* __restrict__ pout,
    int nsplit, int nlen)
{
  const int wg = (int)blockIdx.x;
  const int chunk = (int)gridDim.x >> 3;           // blocks per XCD (bijective)
  const int id2 = (wg & 7) * chunk + (wg >> 3);
  const int per_b = 64 * nsplit;
  const int b = id2 / per_b;
  const int rem = id2 - b * per_b;
  const int ns = rem >> 6;
  const int m0 = (rem & 63) * 64;
  const int nbeg = ns * nlen;

  const int t = threadIdx.x;
  const int w = t >> 6, l = t & 63, h = l >> 5, col = l & 31;
  const int ch = w & 1, mf = w >> 1;
  const int cbase = 128 * ch;
  const int m = m0 + 32 * mf + col;

  const unsigned short* Qb  = Qt + (size_t)b * NN * 32;
  const unsigned short* Kb  = Kt + (size_t)b * NN * 32;
  const unsigned short* Vtb = Vt + (size_t)b * (NN >> 4) * CC * 16;
  const float* cb = cbias + (size_t)b * NN;

  bf16x8 bk0 = ld_frag(Kb + (size_t)m * 32 + 8 * h);
  bf16x8 bk1 = ld_frag(Kb + (size_t)m * 32 + 16 + 8 * h);

  f32x16 acc[4];
#pragma unroll
  for (int cf = 0; cf < 4; ++cf) acc[cf] = zero16();

  const int iters = nlen >> 5;                      // 64 or 128, even
  f32x16 S_c, S_n;
  bf16x8 aqB0, aqB1, aqN0, aqN1;
  bf16x8 V0[8], V1[8];
  f32x4 cbc[4], cbn[4];

  // ---- prologue: Q(0), Q(1), V(0), cb(0), S(0) ----
  {
    bf16x8 aq00 = ld_frag(Qb + (size_t)(nbeg + col) * 32 + 8 * h);
    bf16x8 aq01 = ld_frag(Qb + (size_t)(nbeg + col) * 32 + 16 + 8 * h);
    aqB0 = ld_frag(Qb + (size_t)(nbeg + 32 + col) * 32 + 8 * h);
    aqB1 = ld_frag(Qb + (size_t)(nbeg + 32 + col) * 32 + 16 + 8 * h);
    const unsigned short* vt0_ =
        Vtb + (((size_t)(nbeg >> 4)) * CC + cbase + col) * 16 + 8 * h;
    const unsigned short* vt1_ = vt0_ + (size_t)CC * 16;
    V0[0] = ld_frag(vt0_);
    V0[1] = ld_frag(vt0_ + 32 * 16);
    V0[2] = ld_frag(vt0_ + 64 * 16);
    V0[3] = ld_frag(vt0_ + 96 * 16);
    V0[4] = ld_frag(vt1_);
    V0[5] = ld_frag(vt1_ + 32 * 16);
    V0[6] = ld_frag(vt1_ + 64 * 16);
    V0[7] = ld_frag(vt1_ + 96 * 16);
#pragma unroll
    for (int q = 0; q < 4; ++q) cbc[q] = *(const f32x4*)(cb + nbeg + 8 * q + 4 * h);
    S_c = zero16();
    S_c = mfma32(aq00, bk0, S_c);
    S_c = mfma32(aq01, bk1, S_c);
  }

  for (int tt = 0; tt < iters; tt += 2) {
    PV_BODY(tt,     S_c, S_n, aqB0, aqB1, aqN0, aqN1, V0, V1, cbc, cbn)
    PV_BODY(tt + 1, S_n, S_c, aqN0, aqN1, aqB0, aqB1, V1, V0, cbn, cbc)
  }

  // D-tile: row = m_local, col = c. Store [m][c]-major: coalesced.
  float* pb = pout + (((size_t)ns * NB + b) * NN + (size_t)(m0 + 32 * mf)) * CC + cbase;
#pragma unroll
  for (int cf = 0; cf < 4; ++cf)
#pragma unroll
    for (int r = 0; r < 16; ++r) {
      int mloc = (r & 3) + 8 * (r >> 2) + 4 * h;
      pb[(size_t)mloc * CC + 32 * cf + col] = acc[cf][r];
    }
}

// ---------------- Kernel 4: combine + transpose + residual ----------------
__global__ __launch_bounds__(256) void k_comb(
    const float* __restrict__ pout, const float* __restrict__ x,
    const float* __restrict__ gamma, float* __restrict__ out, int nsplit)
{
  __shared__ float ld[64][65];
  const size_t STRIDE = (size_t)NB * CC * NN;
  const int t = threadIdx.x;
  const int m0 = blockIdx.x * 64, c0 = blockIdx.y * 64, b = blockIdx.z;
  const int ci = t & 63, mo = t >> 6;

  const float* pb = pout + ((size_t)b * NN + m0) * CC + c0;
#pragma unroll
  for (int rep = 0; rep < 16; ++rep) {
    const int mi = 4 * rep + mo;
    float s = pb[(size_t)mi * CC + ci];
    for (int ns = 1; ns < nsplit; ++ns)
      s += pb[ns * STRIDE + (size_t)mi * CC + ci];
    ld[mi][ci] = s;
  }
  __syncthreads();

  const float g = gamma[0];
  const int mi2 = t & 63;
#pragma unroll
  for (int rep = 0; rep < 16; ++rep) {
    const int cj = 4 * rep + mo;
    const size_t idx = ((size_t)b * CC + c0 + cj) * NN + m0 + mi2;
    out[idx] = g * ld[mi2][cj] + x[idx];
  }
}

// ---------------- launch ---------------------------------------------------
extern "C" void kernel_launch(void* const* d_in, const int* in_sizes, int n_in,
                              void* d_out, int out_size, void* d_ws, size_t ws_size,
                              hipStream_t stream) {
  const float* x     = (const float*)d_in[0];
  const float* Wq    = (const float*)d_in[1];
  const float* bq    = (const float*)d_in[2];
  const float* Wk    = (const float*)d_in[3];
  const float* bk    = (const float*)d_in[4];
  const float* Wv    = (const float*)d_in[5];
  const float* bv    = (const float*)d_in[6];
  const float* gamma = (const float*)d_in[7];
  float* out = (float*)d_out;

  char* ws = (char*)d_ws;
  unsigned short* Qt = (unsigned short*)(ws);                      // 1 MB
  unsigned short* Kt = (unsigned short*)(ws + (1u << 20));         // 1 MB
  unsigned short* Vt = (unsigned short*)(ws + (2u << 20));         // 8 MB
  float* pmax  = (float*)(ws + (10u << 20));                       // 256 KB
  float* psum  = (float*)(ws + (10u << 20) + (1u << 18));          // 256 KB
  float* cbias = (float*)(ws + (10u << 20) + (2u << 18));          // 64 KB
  const size_t POUT_OFF = (11u << 20);
  float* pout = (float*)(ws + POUT_OFF);
  const size_t PART_BYTES = (size_t)NB * CC * NN * 4;              // 16 MB

  int nsplit = (ws_size >= POUT_OFF + 2 * PART_BYTES) ? 2 : 1;

  k_proj<<<dim3(NN / 32, NB), 256, 0, stream>>>(x, Wq, bq, Wk, bk, Wv, bv, Qt, Kt, Vt);
  k_rowstats_part<<<dim3(NN / 32, NB, MSPLIT), 256, 0, stream>>>(Qt, Kt, pmax, psum);
  k_statfin<<<dim3(NB * NN / 256), 256, 0, stream>>>(pmax, psum, cbias);
  k_attn_out<<<dim3(256 * nsplit), 256, 0, stream>>>(
      Qt, Kt, Vt, cbias, pout, nsplit, NN / nsplit);
  k_comb<<<dim3(NN / 64, CC / 64, NB), 256, 0, stream>>>(pout, x, gamma, out, nsplit);
}

// Round 7
// 147.682 us; speedup vs baseline: 1.0384x; 1.0384x over previous
//
#include <hip/hip_runtime.h>
#include <hip/hip_bf16.h>

// attention_11269994185437: B=4, C=256, CQK=32, H=W=64 -> N=4096
// out = gamma * (V @ P) + x,  P[n,m] = softmax over m of S[n,m], S = Q^T K.
// Qt pre-scaled by L2E: S' = L2E*S. cbias[b][n] = -max(S') - log2(sum exp2(S'-max)).
// k_attn_out: out^T = E^T * V^T with fp8 V + fp8 E (mfma_f32_32x32x16_fp8_fp8),
//   Q staged frag-linear + V staged [c][16] in LDS via global_load_lds (dbuf),
//   E->fp8 via cvt_pk_fp8 + one permlane32_swap pair per K-half.
// k_comb: sum partials, LDS-transpose [m][c]->[c][m], out = g*sum + x.

#define NB 4
#define CC 256
#define NN 4096
#define MSPLIT 4
#define L2E 1.44269504088896340f

typedef short  short4v  __attribute__((ext_vector_type(4)));
typedef short  short8v  __attribute__((ext_vector_type(8)));
typedef __bf16 bf16x8   __attribute__((ext_vector_type(8)));
typedef float  f32x4    __attribute__((ext_vector_type(4)));
typedef float  f32x16   __attribute__((ext_vector_type(16)));
typedef unsigned int u32;

#define AS1 __attribute__((address_space(1)))
#define AS3 __attribute__((address_space(3)))

static __device__ __forceinline__ void gload16(const void* g, void* l) {
  __builtin_amdgcn_global_load_lds((const AS1 u32*)g, (AS3 u32*)l, 16, 0, 0);
}

static __device__ __forceinline__ unsigned short f2bf(float f) {
  union { __bf16 h; unsigned short u; } v; v.h = (__bf16)f; return v.u;
}

union FragU { short8v s; bf16x8 b; unsigned u[4]; };

static __device__ __forceinline__ bf16x8 ld_frag(const unsigned short* p) {
  FragU u; u.s = *(const short8v*)p; return u.b;
}

static __device__ __forceinline__ f32x16 zero16() {
  f32x16 v;
#pragma unroll
  for (int i = 0; i < 16; ++i) v[i] = 0.0f;
  return v;
}

static __device__ __forceinline__ f32x16 mfma32(bf16x8 a, bf16x8 b, f32x16 c) {
  return __builtin_amdgcn_mfma_f32_32x32x16_bf16(a, b, c, 0, 0, 0);
}

// ---------------- Kernel 1: QKV projection --------------------------------
// Qt[b][n][32] bf16 (L2E-scaled), Kt[b][n][32] bf16, V8[b][n>>4][c][n&15] fp8.
__global__ __launch_bounds__(256) void k_proj(
    const float* __restrict__ x,
    const float* __restrict__ Wq, const float* __restrict__ bq,
    const float* __restrict__ Wk, const float* __restrict__ bk,
    const float* __restrict__ Wv, const float* __restrict__ bv,
    unsigned short* __restrict__ Qt, unsigned short* __restrict__ Kt,
    unsigned char* __restrict__ V8)
{
  __shared__ unsigned short xs[32][268];   // xs[n_local][c]
  const int t = threadIdx.x;
  const int b = blockIdx.y;
  const int n0 = blockIdx.x * 32;
  const int w = t >> 6, l = t & 63, h = l >> 5, col = l & 31;

  const float* xb = x + (size_t)b * CC * NN;
  {
    const int c_off = t >> 3, nl = 4 * (t & 7);
#pragma unroll
    for (int c0 = 0; c0 < CC; c0 += 32) {
      int c = c0 + c_off;
      f32x4 v4 = *(const f32x4*)(xb + (size_t)c * NN + n0 + nl);
#pragma unroll
      for (int j = 0; j < 4; ++j) xs[nl + j][c] = f2bf(v4[j]);
    }
  }
  __syncthreads();

  for (int f = w; f < 10; f += 4) {
    const float* Wsrc; const float* bsrc; int rowbase; int mode;
    if (f == 0)      { Wsrc = Wq; bsrc = bq; rowbase = 0;            mode = 0; }
    else if (f == 1) { Wsrc = Wk; bsrc = bk; rowbase = 0;            mode = 1; }
    else             { Wsrc = Wv; bsrc = bv; rowbase = (f - 2) * 32; mode = 2; }

    f32x16 acc0 = zero16();
    const float* wr = Wsrc + (size_t)(rowbase + col) * CC + 8 * h;

#pragma unroll
    for (int k0 = 0; k0 < CC; k0 += 16) {
      f32x4 w0 = *(const f32x4*)(wr + k0);
      f32x4 w1 = *(const f32x4*)(wr + k0 + 4);
      FragU a;
#pragma unroll
      for (int j = 0; j < 4; ++j) { a.s[j] = (short)f2bf(w0[j]); a.s[4 + j] = (short)f2bf(w1[j]); }
      const unsigned short* p0 = &xs[col][k0 + 8 * h];
      FragU b0;
      short4v t0a = *(const short4v*)p0, t0b = *(const short4v*)(p0 + 4);
#pragma unroll
      for (int j = 0; j < 4; ++j) { b0.s[j] = t0a[j]; b0.s[4 + j] = t0b[j]; }
      acc0 = mfma32(a.b, b0.b, acc0);
    }

    const int n = n0 + col;
#pragma unroll
    for (int q = 0; q < 4; ++q) {
      f32x4 bias4 = *(const f32x4*)(bsrc + rowbase + 8 * q + 4 * h);
      float vals[4];
#pragma unroll
      for (int i = 0; i < 4; ++i) vals[i] = acc0[4 * q + i] + bias4[i];
      if (mode == 2) {
        // V8[b][n>>4][c][n&15], fp8 e4m3
        const size_t tb = ((size_t)b * (NN >> 4) + (n >> 4)) * CC * 16 + (n & 15);
        u32 w01 = __builtin_amdgcn_cvt_pk_fp8_f32(vals[0], vals[1], 0, false);
        u32 w23 = __builtin_amdgcn_cvt_pk_fp8_f32(vals[2], vals[3], 0, false);
        const int cb0 = rowbase + 8 * q + 4 * h;
        V8[tb + (size_t)(cb0 + 0) * 16] = (unsigned char)(w01 & 0xff);
        V8[tb + (size_t)(cb0 + 1) * 16] = (unsigned char)((w01 >> 8) & 0xff);
        V8[tb + (size_t)(cb0 + 2) * 16] = (unsigned char)(w23 & 0xff);
        V8[tb + (size_t)(cb0 + 3) * 16] = (unsigned char)((w23 >> 8) & 0xff);
      } else {
        unsigned short* dst = (mode == 0) ? Qt : Kt;
        const float scale = (mode == 0) ? L2E : 1.0f;   // fold L2E into Q
        short4v s4;
#pragma unroll
        for (int i = 0; i < 4; ++i) s4[i] = (short)f2bf(vals[i] * scale);
        *(short4v*)(dst + ((size_t)b * NN + n) * 32 + 8 * q + 4 * h) = s4;
      }
    }
  }
}

// ---------------- Kernel 2a: partial row stats (single sweep) -------------
__global__ __launch_bounds__(256) void k_rowstats_part(
    const unsigned short* __restrict__ Qt, const unsigned short* __restrict__ Kt,
    float* __restrict__ pmax, float* __restrict__ psum)
{
  __shared__ float smax[4][32], ssum[4][32];
  const int t = threadIdx.x;
  const int w = t >> 6, l = t & 63, h = l >> 5, col = l & 31;
  const int b = blockIdx.y;
  const int n0 = blockIdx.x * 32;
  const int mlen = NN / MSPLIT / 4;                 // 256
  const int mbase = blockIdx.z * (NN / MSPLIT) + w * mlen;
  const unsigned short* Qb = Qt + (size_t)b * NN * 32;
  const unsigned short* Kb = Kt + (size_t)b * NN * 32;

  bf16x8 aq0 = ld_frag(Qb + (size_t)(n0 + col) * 32 + 8 * h);
  bf16x8 aq1 = ld_frag(Qb + (size_t)(n0 + col) * 32 + 16 + 8 * h);

  f32x16 St[8];
#pragma unroll
  for (int mt = 0; mt < 8; ++mt) {
    const int m0 = mbase + mt * 32;
    bf16x8 bk0 = ld_frag(Kb + (size_t)(m0 + col) * 32 + 8 * h);
    bf16x8 bk1 = ld_frag(Kb + (size_t)(m0 + col) * 32 + 16 + 8 * h);
    f32x16 S = zero16();
    S = mfma32(aq0, bk0, S);
    St[mt] = mfma32(aq1, bk1, S);
  }

  float mx[16];
#pragma unroll
  for (int r = 0; r < 16; ++r) mx[r] = -3.4e38f;
#pragma unroll
  for (int mt = 0; mt < 8; ++mt)
#pragma unroll
    for (int r = 0; r < 16; ++r) mx[r] = fmaxf(mx[r], St[mt][r]);
#pragma unroll
  for (int off = 1; off < 32; off <<= 1)
#pragma unroll
    for (int r = 0; r < 16; ++r) mx[r] = fmaxf(mx[r], __shfl_xor(mx[r], off));

  float sm[16];
#pragma unroll
  for (int r = 0; r < 16; ++r) sm[r] = 0.0f;
#pragma unroll
  for (int mt = 0; mt < 8; ++mt)
#pragma unroll
    for (int r = 0; r < 16; ++r) sm[r] += __builtin_amdgcn_exp2f(St[mt][r] - mx[r]);
#pragma unroll
  for (int off = 1; off < 32; off <<= 1)
#pragma unroll
    for (int r = 0; r < 16; ++r) sm[r] += __shfl_xor(sm[r], off);

  if (col == 0) {
#pragma unroll
    for (int r = 0; r < 16; ++r) {
      int nl = (r & 3) + 8 * (r >> 2) + 4 * h;
      smax[w][nl] = mx[r];
      ssum[w][nl] = sm[r];
    }
  }
  __syncthreads();

  if (t < 32) {
    float gm = smax[0][t];
#pragma unroll
    for (int wv = 1; wv < 4; ++wv) gm = fmaxf(gm, smax[wv][t]);
    float s = 0.0f;
#pragma unroll
    for (int wv = 0; wv < 4; ++wv)
      s += ssum[wv][t] * __builtin_amdgcn_exp2f(smax[wv][t] - gm);
    const size_t base = ((size_t)b * MSPLIT + blockIdx.z) * NN;
    pmax[base + n0 + t] = gm;
    psum[base + n0 + t] = s;
  }
}

// ---------------- Kernel 2b: combine -> cbias = -max' - log2(sum) ---------
__global__ __launch_bounds__(256) void k_statfin(
    const float* __restrict__ pmax, const float* __restrict__ psum,
    float* __restrict__ cbias)
{
  const int i = blockIdx.x * 256 + threadIdx.x;
  const int b = i >> 12, n = i & (NN - 1);
  float pm[MSPLIT], ps[MSPLIT];
#pragma unroll
  for (int s = 0; s < MSPLIT; ++s) {
    pm[s] = pmax[((size_t)b * MSPLIT + s) * NN + n];
    ps[s] = psum[((size_t)b * MSPLIT + s) * NN + n];
  }
  float gmax = pm[0];
#pragma unroll
  for (int s = 1; s < MSPLIT; ++s) gmax = fmaxf(gmax, pm[s]);
  float gsum = 0.0f;
#pragma unroll
  for (int s = 0; s < MSPLIT; ++s) gsum += ps[s] * __builtin_amdgcn_exp2f(pm[s] - gmax);
  cbias[i] = -gmax - __builtin_amdgcn_logf(gsum);
}

// ---------------- Kernel 3: out^T = E^T * V^T, fp8, LDS-staged ------------
// grid 256*nsplit (XCD-swizzled), 4 waves. Wave: ch=w&1 (128 c), mf=w>>1 (32 m).
// LDS per buffer: [0,2048) Q frag-linear (frag f at f*1024 + lane*16);
//                 [2048,10240) V8 [nt][c][16]. Double buffered.
__global__ __launch_bounds__(256) void k_attn_out(
    const unsigned short* __restrict__ Qt, const unsigned short* __restrict__ Kt,
    const unsigned char* __restrict__ V8,
    const float* __restrict__ cbias,
    float* __restrict__ pout,
    int nsplit, int nlen)
{
  __shared__ __align__(16) char smem[2][10240];

  const int wg = (int)blockIdx.x;
  const int chunk = (int)gridDim.x >> 3;           // blocks per XCD (bijective)
  const int id2 = (wg & 7) * chunk + (wg >> 3);
  const int per_b = 64 * nsplit;
  const int b = id2 / per_b;
  const int rem = id2 - b * per_b;
  const int ns = rem >> 6;
  const int m0 = (rem & 63) * 64;
  const int nbeg = ns * nlen;

  const int t = threadIdx.x;
  const int w = t >> 6, l = t & 63, h = l >> 5, col = l & 31;
  const int ch = w & 1, mf = w >> 1;
  const int cbase = 128 * ch;
  const int m = m0 + 32 * mf + col;

  const unsigned short* Kb = Kt + (size_t)b * NN * 32;
  const float* cb = cbias + (size_t)b * NN + nbeg;

  // loop-invariant K fragments (B operand of S)
  bf16x8 bk0 = ld_frag(Kb + (size_t)m * 32 + 8 * h);
  bf16x8 bk1 = ld_frag(Kb + (size_t)m * 32 + 16 + 8 * h);

  // staging source pointers (per lane)
  const char* qsrc = (const char*)Qt + ((size_t)b * NN + nbeg) * 64
                     + (size_t)(l & 31) * 64 + (l >> 5) * 16 + w * 32;  // w<2 only
  const char* vsrc = (const char*)V8 + ((size_t)b * (NN >> 4) + (nbeg >> 4)) * CC * 16
                     + (size_t)(w * 64 + l) * 16;

  f32x16 acc[4];
#pragma unroll
  for (int cf = 0; cf < 4; ++cf) acc[cf] = zero16();

  const int iters = nlen >> 5;

  // ---- prologue: stage tile 0 into buf 0 ----
  if (w < 2) gload16(qsrc, &smem[0][w * 1024]);
  gload16(vsrc,        &smem[0][2048 + w * 1024]);
  gload16(vsrc + 4096, &smem[0][2048 + 4096 + w * 1024]);
  qsrc += 2048; vsrc += 8192;
  __syncthreads();

  for (int it = 0; it < iters; ++it) {
    const int p = it & 1;
    // ---- stage next tile into buf p^1 ----
    if (it + 1 < iters) {
      if (w < 2) gload16(qsrc, &smem[p ^ 1][w * 1024]);
      gload16(vsrc,        &smem[p ^ 1][2048 + w * 1024]);
      gload16(vsrc + 4096, &smem[p ^ 1][2048 + 4096 + w * 1024]);
      qsrc += 2048; vsrc += 8192;
    }

    // ---- Q frags from LDS (frag-linear: conflict-free b128) ----
    FragU fq0, fq1;
    fq0.s = *(const short8v*)(&smem[p][l * 16]);
    fq1.s = *(const short8v*)(&smem[p][1024 + l * 16]);

    // ---- V^T B-frags from LDS (b64, bank-even) ----
    const char* vb = &smem[p][2048 + (cbase + col) * 16 + 8 * h];
    long bv00 = *(const long*)(vb);
    long bv01 = *(const long*)(vb + 32 * 16);
    long bv02 = *(const long*)(vb + 64 * 16);
    long bv03 = *(const long*)(vb + 96 * 16);
    long bv10 = *(const long*)(vb + 4096);
    long bv11 = *(const long*)(vb + 4096 + 32 * 16);
    long bv12 = *(const long*)(vb + 4096 + 64 * 16);
    long bv13 = *(const long*)(vb + 4096 + 96 * 16);

    // ---- S' = Q'^T K ----
    f32x16 S = zero16();
    S = mfma32(fq0.b, bk0, S);
    S = mfma32(fq1.b, bk1, S);

    // ---- E = exp2(S' + cbias[n]) -> fp8, relayout via permlane32_swap ----
    float e[16];
#pragma unroll
    for (int q = 0; q < 4; ++q) {
      f32x4 cb4 = *(const f32x4*)(cb + 8 * q + 4 * h);
#pragma unroll
      for (int i = 0; i < 4; ++i)
        e[4 * q + i] = __builtin_amdgcn_exp2f(S[4 * q + i] + cb4[i]);
    }
    u32 wA = __builtin_amdgcn_cvt_pk_fp8_f32(e[0], e[1], 0, false);
    wA = __builtin_amdgcn_cvt_pk_fp8_f32(e[2], e[3], wA, true);
    u32 wB = __builtin_amdgcn_cvt_pk_fp8_f32(e[4], e[5], 0, false);
    wB = __builtin_amdgcn_cvt_pk_fp8_f32(e[6], e[7], wB, true);
    u32 wC = __builtin_amdgcn_cvt_pk_fp8_f32(e[8], e[9], 0, false);
    wC = __builtin_amdgcn_cvt_pk_fp8_f32(e[10], e[11], wC, true);
    u32 wD = __builtin_amdgcn_cvt_pk_fp8_f32(e[12], e[13], 0, false);
    wD = __builtin_amdgcn_cvt_pk_fp8_f32(e[14], e[15], wD, true);
    // (r0,r1) = swap(wA,wB): every lane gets its E^T A-frag words for kh0
    asm("v_permlane32_swap_b32 %0, %1" : "+v"(wA), "+v"(wB));
    asm("v_permlane32_swap_b32 %0, %1" : "+v"(wC), "+v"(wD));
    long A0 = (long)(((unsigned long)wB << 32) | wA);
    long A1 = (long)(((unsigned long)wD << 32) | wC);

    // ---- out^T += E^T * V^T (fp8 MFMA) ----
    acc[0] = __builtin_amdgcn_mfma_f32_32x32x16_fp8_fp8(A0, bv00, acc[0], 0, 0, 0);
    acc[0] = __builtin_amdgcn_mfma_f32_32x32x16_fp8_fp8(A1, bv10, acc[0], 0, 0, 0);
    acc[1] = __builtin_amdgcn_mfma_f32_32x32x16_fp8_fp8(A0, bv01, acc[1], 0, 0, 0);
    acc[1] = __builtin_amdgcn_mfma_f32_32x32x16_fp8_fp8(A1, bv11, acc[1], 0, 0, 0);
    acc[2] = __builtin_amdgcn_mfma_f32_32x32x16_fp8_fp8(A0, bv02, acc[2], 0, 0, 0);
    acc[2] = __builtin_amdgcn_mfma_f32_32x32x16_fp8_fp8(A1, bv12, acc[2], 0, 0, 0);
    acc[3] = __builtin_amdgcn_mfma_f32_32x32x16_fp8_fp8(A0, bv03, acc[3], 0, 0, 0);
    acc[3] = __builtin_amdgcn_mfma_f32_32x32x16_fp8_fp8(A1, bv13, acc[3], 0, 0, 0);

    cb += 32;
    __syncthreads();   // buf p^1 staged; buf p reads done
  }

  // D-tile: row = m_local, col = c. Store [m][c]-major: coalesced.
  float* pb = pout + (((size_t)ns * NB + b) * NN + (size_t)(m0 + 32 * mf)) * CC + cbase;
#pragma unroll
  for (int cf = 0; cf < 4; ++cf)
#pragma unroll
    for (int r = 0; r < 16; ++r) {
      int mloc = (r & 3) + 8 * (r >> 2) + 4 * h;
      pb[(size_t)mloc * CC + 32 * cf + col] = acc[cf][r];
    }
}

// ---------------- Kernel 4: combine + transpose + residual ----------------
__global__ __launch_bounds__(256) void k_comb(
    const float* __restrict__ pout, const float* __restrict__ x,
    const float* __restrict__ gamma, float* __restrict__ out, int nsplit)
{
  __shared__ float ld[64][65];
  const size_t STRIDE = (size_t)NB * CC * NN;
  const int t = threadIdx.x;
  const int m0 = blockIdx.x * 64, c0 = blockIdx.y * 64, b = blockIdx.z;
  const int ci = t & 63, mo = t >> 6;

  const float* pb = pout + ((size_t)b * NN + m0) * CC + c0;
#pragma unroll
  for (int rep = 0; rep < 16; ++rep) {
    const int mi = 4 * rep + mo;
    float s = pb[(size_t)mi * CC + ci];
    for (int ns = 1; ns < nsplit; ++ns)
      s += pb[ns * STRIDE + (size_t)mi * CC + ci];
    ld[mi][ci] = s;
  }
  __syncthreads();

  const float g = gamma[0];
  const int mi2 = t & 63;
#pragma unroll
  for (int rep = 0; rep < 16; ++rep) {
    const int cj = 4 * rep + mo;
    const size_t idx = ((size_t)b * CC + c0 + cj) * NN + m0 + mi2;
    out[idx] = g * ld[mi2][cj] + x[idx];
  }
}

// ---------------- launch ---------------------------------------------------
extern "C" void kernel_launch(void* const* d_in, const int* in_sizes, int n_in,
                              void* d_out, int out_size, void* d_ws, size_t ws_size,
                              hipStream_t stream) {
  const float* x     = (const float*)d_in[0];
  const float* Wq    = (const float*)d_in[1];
  const float* bq    = (const float*)d_in[2];
  const float* Wk    = (const float*)d_in[3];
  const float* bk    = (const float*)d_in[4];
  const float* Wv    = (const float*)d_in[5];
  const float* bv    = (const float*)d_in[6];
  const float* gamma = (const float*)d_in[7];
  float* out = (float*)d_out;

  char* ws = (char*)d_ws;
  unsigned short* Qt = (unsigned short*)(ws);                      // 1 MB
  unsigned short* Kt = (unsigned short*)(ws + (1u << 20));         // 1 MB
  unsigned char*  V8 = (unsigned char*)(ws + (2u << 20));          // 4 MB
  float* pmax  = (float*)(ws + (10u << 20));                       // 256 KB
  float* psum  = (float*)(ws + (10u << 20) + (1u << 18));          // 256 KB
  float* cbias = (float*)(ws + (10u << 20) + (2u << 18));          // 64 KB
  const size_t POUT_OFF = (11u << 20);
  float* pout = (float*)(ws + POUT_OFF);
  const size_t PART_BYTES = (size_t)NB * CC * NN * 4;              // 16 MB

  int nsplit = (ws_size >= POUT_OFF + 2 * PART_BYTES) ? 2 : 1;

  k_proj<<<dim3(NN / 32, NB), 256, 0, stream>>>(x, Wq, bq, Wk, bk, Wv, bv, Qt, Kt, V8);
  k_rowstats_part<<<dim3(NN / 32, NB, MSPLIT), 256, 0, stream>>>(Qt, Kt, pmax, psum);
  k_statfin<<<dim3(NB * NN / 256), 256, 0, stream>>>(pmax, psum, cbias);
  k_attn_out<<<dim3(256 * nsplit), 256, 0, stream>>>(
      Qt, Kt, V8, cbias, pout, nsplit, NN / nsplit);
  k_comb<<<dim3(NN / 64, CC / 64, NB), 256, 0, stream>>>(pout, x, gamma, out, nsplit);
}

// Round 8
// 139.559 us; speedup vs baseline: 1.0989x; 1.0582x over previous
//
#include <hip/hip_runtime.h>
#include <hip/hip_bf16.h>

// attention_11269994185437: B=4, C=256, CQK=32, H=W=64 -> N=4096
// out = gamma * (V @ P) + x,  P[n,m] = softmax over m of S[n,m], S = Q^T K.
// Qt pre-scaled by L2E: S' = L2E*S. cbias[b][n] = -max(S') - log2(sum exp2(S'-max)).
// k_attn_out: out^T = E^T * V^T, producer/consumer wave specialization:
//   waves 0-3 (producers): S = Q'K (bf16 MFMA), E = exp2(S'+cb) -> fp8 A-frags
//                          via cvt_pk_fp8 + permlane32_swap, write to LDS.
//   waves 4-7 (consumers): read E(t-1) + V(t-1) from LDS, 16 fp8 MFMAs each.
//   Q 2-buf, V 3-buf (consumers lag 1 tile), E 2-buf; one barrier/iter.
// k_comb: sum partials, LDS-transpose [m][c]->[c][m], out = g*sum + x.

#define NB 4
#define CC 256
#define NN 4096
#define MSPLIT 4
#define L2E 1.44269504088896340f

typedef short  short4v  __attribute__((ext_vector_type(4)));
typedef short  short8v  __attribute__((ext_vector_type(8)));
typedef __bf16 bf16x8   __attribute__((ext_vector_type(8)));
typedef float  f32x4    __attribute__((ext_vector_type(4)));
typedef float  f32x16   __attribute__((ext_vector_type(16)));
typedef unsigned long u64x2 __attribute__((ext_vector_type(2)));
typedef unsigned int u32;

#define AS1 __attribute__((address_space(1)))
#define AS3 __attribute__((address_space(3)))

static __device__ __forceinline__ void gload16(const void* g, void* l) {
  __builtin_amdgcn_global_load_lds((const AS1 u32*)g, (AS3 u32*)l, 16, 0, 0);
}

static __device__ __forceinline__ unsigned short f2bf(float f) {
  union { __bf16 h; unsigned short u; } v; v.h = (__bf16)f; return v.u;
}

union FragU { short8v s; bf16x8 b; unsigned u[4]; };

static __device__ __forceinline__ bf16x8 ld_frag(const unsigned short* p) {
  FragU u; u.s = *(const short8v*)p; return u.b;
}

static __device__ __forceinline__ f32x16 zero16() {
  f32x16 v;
#pragma unroll
  for (int i = 0; i < 16; ++i) v[i] = 0.0f;
  return v;
}

static __device__ __forceinline__ f32x16 mfma32(bf16x8 a, bf16x8 b, f32x16 c) {
  return __builtin_amdgcn_mfma_f32_32x32x16_bf16(a, b, c, 0, 0, 0);
}

// ---------------- Kernel 0: W -> bf16 row-major [320][256] ----------------
// rows 0-31 Wq, 32-63 Wk, 64-319 Wv.
__global__ __launch_bounds__(256) void k_wcvt(
    const float* __restrict__ Wq, const float* __restrict__ Wk,
    const float* __restrict__ Wv, unsigned short* __restrict__ Wb)
{
  const int i4 = blockIdx.x * 256 + threadIdx.x;     // 80 blocks
  const int e = i4 * 4;
  const int row = e >> 8, c = e & 255;
  const float* src = (row < 32) ? (Wq + row * 256 + c)
                   : (row < 64) ? (Wk + (row - 32) * 256 + c)
                                : (Wv + (row - 64) * 256 + c);
  f32x4 v = *(const f32x4*)src;
  short4v s;
#pragma unroll
  for (int j = 0; j < 4; ++j) s[j] = (short)f2bf(v[j]);
  *(short4v*)(Wb + e) = s;
}

// ---------------- Kernel 1: QKV projection --------------------------------
// Qt[b][n][32] bf16 (L2E-scaled), Kt[b][n][32] bf16,
// V8[b][nt16][kh][c][8] fp8 e4m3 (kh = (n&15)>>3).
__global__ __launch_bounds__(256) void k_proj(
    const float* __restrict__ x, const unsigned short* __restrict__ Wb,
    const float* __restrict__ bq, const float* __restrict__ bk,
    const float* __restrict__ bv,
    unsigned short* __restrict__ Qt, unsigned short* __restrict__ Kt,
    unsigned char* __restrict__ V8)
{
  __shared__ unsigned short xs[32][268];   // xs[n_local][c]
  const int t = threadIdx.x;
  const int b = blockIdx.y;
  const int n0 = blockIdx.x * 32;
  const int w = t >> 6, l = t & 63, h = l >> 5, col = l & 31;

  const float* xb = x + (size_t)b * CC * NN;
  {
    const int c_off = t >> 3, nl = 4 * (t & 7);
#pragma unroll
    for (int c0 = 0; c0 < CC; c0 += 32) {
      int c = c0 + c_off;
      f32x4 v4 = *(const f32x4*)(xb + (size_t)c * NN + n0 + nl);
#pragma unroll
      for (int j = 0; j < 4; ++j) xs[nl + j][c] = f2bf(v4[j]);
    }
  }
  __syncthreads();

  for (int f = w; f < 10; f += 4) {
    const float* bsrc; int rowbase; int mode; int wrow;
    if (f == 0)      { bsrc = bq; rowbase = 0;            mode = 0; wrow = 0; }
    else if (f == 1) { bsrc = bk; rowbase = 0;            mode = 1; wrow = 32; }
    else             { bsrc = bv; rowbase = (f - 2) * 32; mode = 2; wrow = 64 + rowbase; }

    f32x16 acc0 = zero16();
    const unsigned short* wr = Wb + (size_t)(wrow + col) * 256 + 8 * h;

#pragma unroll
    for (int k0 = 0; k0 < CC; k0 += 16) {
      FragU a;
      a.s = *(const short8v*)(wr + k0);
      const unsigned short* p0 = &xs[col][k0 + 8 * h];
      FragU b0;
      short4v t0a = *(const short4v*)p0, t0b = *(const short4v*)(p0 + 4);
#pragma unroll
      for (int j = 0; j < 4; ++j) { b0.s[j] = t0a[j]; b0.s[4 + j] = t0b[j]; }
      acc0 = mfma32(a.b, b0.b, acc0);
    }

    const int n = n0 + col;
#pragma unroll
    for (int q = 0; q < 4; ++q) {
      f32x4 bias4 = *(const f32x4*)(bsrc + rowbase + 8 * q + 4 * h);
      float vals[4];
#pragma unroll
      for (int i = 0; i < 4; ++i) vals[i] = acc0[4 * q + i] + bias4[i];
      if (mode == 2) {
        // V8[b][n>>4][(n&15)>>3][c][n&7]
        const size_t tb = (((size_t)b * (NN >> 4) + (n >> 4)) * 2 + ((n >> 3) & 1)) * CC * 8
                          + (n & 7);
        u32 w01 = __builtin_amdgcn_cvt_pk_fp8_f32(vals[0], vals[1], 0, false);
        u32 w23 = __builtin_amdgcn_cvt_pk_fp8_f32(vals[2], vals[3], 0, false);
        const int cb0 = rowbase + 8 * q + 4 * h;
        V8[tb + (size_t)(cb0 + 0) * 8] = (unsigned char)(w01 & 0xff);
        V8[tb + (size_t)(cb0 + 1) * 8] = (unsigned char)((w01 >> 8) & 0xff);
        V8[tb + (size_t)(cb0 + 2) * 8] = (unsigned char)(w23 & 0xff);
        V8[tb + (size_t)(cb0 + 3) * 8] = (unsigned char)((w23 >> 8) & 0xff);
      } else {
        unsigned short* dst = (mode == 0) ? Qt : Kt;
        const float scale = (mode == 0) ? L2E : 1.0f;   // fold L2E into Q
        short4v s4;
#pragma unroll
        for (int i = 0; i < 4; ++i) s4[i] = (short)f2bf(vals[i] * scale);
        *(short4v*)(dst + ((size_t)b * NN + n) * 32 + 8 * q + 4 * h) = s4;
      }
    }
  }
}

// ---------------- Kernel 2a: partial row stats (single sweep) -------------
__global__ __launch_bounds__(256) void k_rowstats_part(
    const unsigned short* __restrict__ Qt, const unsigned short* __restrict__ Kt,
    float* __restrict__ pmax, float* __restrict__ psum)
{
  __shared__ float smax[4][32], ssum[4][32];
  const int t = threadIdx.x;
  const int w = t >> 6, l = t & 63, h = l >> 5, col = l & 31;
  const int b = blockIdx.y;
  const int n0 = blockIdx.x * 32;
  const int mlen = NN / MSPLIT / 4;                 // 256
  const int mbase = blockIdx.z * (NN / MSPLIT) + w * mlen;
  const unsigned short* Qb = Qt + (size_t)b * NN * 32;
  const unsigned short* Kb = Kt + (size_t)b * NN * 32;

  bf16x8 aq0 = ld_frag(Qb + (size_t)(n0 + col) * 32 + 8 * h);
  bf16x8 aq1 = ld_frag(Qb + (size_t)(n0 + col) * 32 + 16 + 8 * h);

  f32x16 St[8];
#pragma unroll
  for (int mt = 0; mt < 8; ++mt) {
    const int m0 = mbase + mt * 32;
    bf16x8 bk0 = ld_frag(Kb + (size_t)(m0 + col) * 32 + 8 * h);
    bf16x8 bk1 = ld_frag(Kb + (size_t)(m0 + col) * 32 + 16 + 8 * h);
    f32x16 S = zero16();
    S = mfma32(aq0, bk0, S);
    St[mt] = mfma32(aq1, bk1, S);
  }

  float mx[16];
#pragma unroll
  for (int r = 0; r < 16; ++r) mx[r] = -3.4e38f;
#pragma unroll
  for (int mt = 0; mt < 8; ++mt)
#pragma unroll
    for (int r = 0; r < 16; ++r) mx[r] = fmaxf(mx[r], St[mt][r]);
#pragma unroll
  for (int off = 1; off < 32; off <<= 1)
#pragma unroll
    for (int r = 0; r < 16; ++r) mx[r] = fmaxf(mx[r], __shfl_xor(mx[r], off));

  float sm[16];
#pragma unroll
  for (int r = 0; r < 16; ++r) sm[r] = 0.0f;
#pragma unroll
  for (int mt = 0; mt < 8; ++mt)
#pragma unroll
    for (int r = 0; r < 16; ++r) sm[r] += __builtin_amdgcn_exp2f(St[mt][r] - mx[r]);
#pragma unroll
  for (int off = 1; off < 32; off <<= 1)
#pragma unroll
    for (int r = 0; r < 16; ++r) sm[r] += __shfl_xor(sm[r], off);

  if (col == 0) {
#pragma unroll
    for (int r = 0; r < 16; ++r) {
      int nl = (r & 3) + 8 * (r >> 2) + 4 * h;
      smax[w][nl] = mx[r];
      ssum[w][nl] = sm[r];
    }
  }
  __syncthreads();

  if (t < 32) {
    float gm = smax[0][t];
#pragma unroll
    for (int wv = 1; wv < 4; ++wv) gm = fmaxf(gm, smax[wv][t]);
    float s = 0.0f;
#pragma unroll
    for (int wv = 0; wv < 4; ++wv)
      s += ssum[wv][t] * __builtin_amdgcn_exp2f(smax[wv][t] - gm);
    const size_t base = ((size_t)b * MSPLIT + blockIdx.z) * NN;
    pmax[base + n0 + t] = gm;
    psum[base + n0 + t] = s;
  }
}

// ---------------- Kernel 2b: combine -> cbias = -max' - log2(sum) ---------
__global__ __launch_bounds__(256) void k_statfin(
    const float* __restrict__ pmax, const float* __restrict__ psum,
    float* __restrict__ cbias)
{
  const int i = blockIdx.x * 256 + threadIdx.x;
  const int b = i >> 12, n = i & (NN - 1);
  float pm[MSPLIT], ps[MSPLIT];
#pragma unroll
  for (int s = 0; s < MSPLIT; ++s) {
    pm[s] = pmax[((size_t)b * MSPLIT + s) * NN + n];
    ps[s] = psum[((size_t)b * MSPLIT + s) * NN + n];
  }
  float gmax = pm[0];
#pragma unroll
  for (int s = 1; s < MSPLIT; ++s) gmax = fmaxf(gmax, pm[s]);
  float gsum = 0.0f;
#pragma unroll
  for (int s = 0; s < MSPLIT; ++s) gsum += ps[s] * __builtin_amdgcn_exp2f(pm[s] - gmax);
  cbias[i] = -gmax - __builtin_amdgcn_logf(gsum);
}

// ---------------- Kernel 3: out^T = E^T * V^T, producer/consumer ----------
// grid 128*nsplit (XCD-swizzled), 8 waves (512 thr). m-tile 128, all 256 c.
// waves 0-3: producer for m-frag w.  waves 4-7: consumer for c-quarter w-4.
__global__ __launch_bounds__(512) void k_attn_out(
    const unsigned short* __restrict__ Qt, const unsigned short* __restrict__ Kt,
    const unsigned char* __restrict__ V8,
    const float* __restrict__ cbias,
    float* __restrict__ pout,
    int nsplit, int nlen)
{
  __shared__ __align__(16) char qbuf[2][2048];   // Q frag-linear per n-tile
  __shared__ __align__(16) char vbuf[3][8192];   // V [t16][kh][c][8] per n-tile
  __shared__ __align__(16) char ebuf[2][4096];   // E A-frags [mf][lane][16B]

  const int wg = (int)blockIdx.x;
  const int chunk = (int)gridDim.x >> 3;           // blocks per XCD (bijective)
  const int id2 = (wg & 7) * chunk + (wg >> 3);
  const int per_b = 32 * nsplit;                   // m-tiles(128) per batch * nsplit
  const int b = id2 / per_b;
  const int rem = id2 - b * per_b;
  const int ns = rem >> 5;
  const int m0 = (rem & 31) * 128;
  const int nbeg = ns * nlen;

  const int t = threadIdx.x;
  const int w = t >> 6, l = t & 63, h = l >> 5, col = l & 31;
  const int mfp = w & 3;                           // producer m-frag
  const int ccons = (w & 3) * 64;                  // consumer c-quarter

  const unsigned short* Kb = Kt + (size_t)b * NN * 32;
  const float* cb = cbias + (size_t)b * NN + nbeg;

  // producer K fragments (B operand of S), loop-invariant
  bf16x8 bk0 = ld_frag(Kb + (size_t)(m0 + 32 * mfp + col) * 32 + 8 * h);
  bf16x8 bk1 = ld_frag(Kb + (size_t)(m0 + 32 * mfp + col) * 32 + 16 + 8 * h);

  // staging sources
  const char* qsrc = (const char*)Qt + ((size_t)b * NN + nbeg) * 64
                     + (size_t)(t & 31) * 64 + ((t >> 5) & 1) * 16 + (t >> 6) * 32;
  const char* vsrc = (const char*)V8 + ((size_t)b * (NN >> 4) + (nbeg >> 4)) * 4096
                     + (size_t)t * 16;

  f32x16 acc[4][2];
#pragma unroll
  for (int mf = 0; mf < 4; ++mf)
#pragma unroll
    for (int cf = 0; cf < 2; ++cf) acc[mf][cf] = zero16();

  const int iters = nlen >> 5;

  // ---- prologue: stage tile 0 ----
  if (t < 128) gload16(qsrc, &qbuf[0][(t >> 6) * 1024]);
  gload16(vsrc, &vbuf[0][w * 1024]);
  __syncthreads();

  for (int it = 0; it <= iters; ++it) {
    // ---- stage tile it+1 ----
    if (it + 1 < iters) {
      if (t < 128)
        gload16(qsrc + (size_t)(it + 1) * 2048, &qbuf[(it + 1) & 1][(t >> 6) * 1024]);
      gload16(vsrc + (size_t)(it + 1) * 8192, &vbuf[(it + 1) % 3][w * 1024]);
    }

    if (w < 4) {
      if (it < iters) {
        // ---- producer: S' = Q'K, E = exp2(S'+cb) -> fp8 A-frags -> LDS ----
        const char* qb = &qbuf[it & 1][0];
        FragU fq0, fq1;
        fq0.s = *(const short8v*)(qb + l * 16);
        fq1.s = *(const short8v*)(qb + 1024 + l * 16);
        f32x16 S = zero16();
        S = mfma32(fq0.b, bk0, S);
        S = mfma32(fq1.b, bk1, S);

        float e[16];
        const float* cbi = cb + it * 32;
#pragma unroll
        for (int q = 0; q < 4; ++q) {
          f32x4 cb4 = *(const f32x4*)(cbi + 8 * q + 4 * h);
#pragma unroll
          for (int i = 0; i < 4; ++i)
            e[4 * q + i] = __builtin_amdgcn_exp2f(S[4 * q + i] + cb4[i]);
        }
        u32 wA = __builtin_amdgcn_cvt_pk_fp8_f32(e[0], e[1], 0, false);
        wA = __builtin_amdgcn_cvt_pk_fp8_f32(e[2], e[3], wA, true);
        u32 wB = __builtin_amdgcn_cvt_pk_fp8_f32(e[4], e[5], 0, false);
        wB = __builtin_amdgcn_cvt_pk_fp8_f32(e[6], e[7], wB, true);
        u32 wC = __builtin_amdgcn_cvt_pk_fp8_f32(e[8], e[9], 0, false);
        wC = __builtin_amdgcn_cvt_pk_fp8_f32(e[10], e[11], wC, true);
        u32 wD = __builtin_amdgcn_cvt_pk_fp8_f32(e[12], e[13], 0, false);
        wD = __builtin_amdgcn_cvt_pk_fp8_f32(e[14], e[15], wD, true);
        asm("v_permlane32_swap_b32 %0, %1" : "+v"(wA), "+v"(wB));
        asm("v_permlane32_swap_b32 %0, %1" : "+v"(wC), "+v"(wD));
        u64x2 ev;
        ev[0] = ((unsigned long)wB << 32) | wA;   // A0: n' 0..15
        ev[1] = ((unsigned long)wD << 32) | wC;   // A1: n' 16..31
        *(u64x2*)(&ebuf[it & 1][mfp * 1024 + l * 16]) = ev;
      }
    } else {
      if (it > 0) {
        // ---- consumer: PV for tile it-1 ----
        const char* vb = &vbuf[(it - 1) % 3][h * 2048 + (ccons + col) * 8];
        long v00 = *(const long*)(vb);             // t16=0, cf=0
        long v01 = *(const long*)(vb + 256);       // t16=0, cf=1
        long v10 = *(const long*)(vb + 4096);      // t16=1, cf=0
        long v11 = *(const long*)(vb + 4096 + 256);
        const char* eb = &ebuf[(it - 1) & 1][l * 16];
        __builtin_amdgcn_s_setprio(1);
#pragma unroll
        for (int mf = 0; mf < 4; ++mf) {
          u64x2 ev = *(const u64x2*)(eb + mf * 1024);
          acc[mf][0] = __builtin_amdgcn_mfma_f32_32x32x16_fp8_fp8(
              (long)ev[0], v00, acc[mf][0], 0, 0, 0);
          acc[mf][0] = __builtin_amdgcn_mfma_f32_32x32x16_fp8_fp8(
              (long)ev[1], v10, acc[mf][0], 0, 0, 0);
          acc[mf][1] = __builtin_amdgcn_mfma_f32_32x32x16_fp8_fp8(
              (long)ev[0], v01, acc[mf][1], 0, 0, 0);
          acc[mf][1] = __builtin_amdgcn_mfma_f32_32x32x16_fp8_fp8(
              (long)ev[1], v11, acc[mf][1], 0, 0, 0);
        }
        __builtin_amdgcn_s_setprio(0);
      }
    }

    if (it < iters) __syncthreads();
  }

  // ---- consumer epilogue: write D tiles [m][c]-major (coalesced) ----
  if (w >= 4) {
    float* pb = pout + (((size_t)ns * NB + b) * NN + m0) * CC + ccons;
#pragma unroll
    for (int mf = 0; mf < 4; ++mf)
#pragma unroll
      for (int cf = 0; cf < 2; ++cf)
#pragma unroll
        for (int r = 0; r < 16; ++r) {
          int mloc = 32 * mf + (r & 3) + 8 * (r >> 2) + 4 * h;
          pb[(size_t)mloc * CC + 32 * cf + col] = acc[mf][cf][r];
        }
  }
}

// ---------------- Kernel 4: combine + transpose + residual ----------------
__global__ __launch_bounds__(256) void k_comb(
    const float* __restrict__ pout, const float* __restrict__ x,
    const float* __restrict__ gamma, float* __restrict__ out, int nsplit)
{
  __shared__ float ld[64][65];
  const size_t STRIDE = (size_t)NB * CC * NN;
  const int t = threadIdx.x;
  const int m0 = blockIdx.x * 64, c0 = blockIdx.y * 64, b = blockIdx.z;
  const int ci = t & 63, mo = t >> 6;

  const float* pb = pout + ((size_t)b * NN + m0) * CC + c0;
#pragma unroll
  for (int rep = 0; rep < 16; ++rep) {
    const int mi = 4 * rep + mo;
    float s = pb[(size_t)mi * CC + ci];
    for (int ns = 1; ns < nsplit; ++ns)
      s += pb[ns * STRIDE + (size_t)mi * CC + ci];
    ld[mi][ci] = s;
  }
  __syncthreads();

  const float g = gamma[0];
  const int mi2 = t & 63;
#pragma unroll
  for (int rep = 0; rep < 16; ++rep) {
    const int cj = 4 * rep + mo;
    const size_t idx = ((size_t)b * CC + c0 + cj) * NN + m0 + mi2;
    out[idx] = g * ld[mi2][cj] + x[idx];
  }
}

// ---------------- launch ---------------------------------------------------
extern "C" void kernel_launch(void* const* d_in, const int* in_sizes, int n_in,
                              void* d_out, int out_size, void* d_ws, size_t ws_size,
                              hipStream_t stream) {
  const float* x     = (const float*)d_in[0];
  const float* Wq    = (const float*)d_in[1];
  const float* bq    = (const float*)d_in[2];
  const float* Wk    = (const float*)d_in[3];
  const float* bk    = (const float*)d_in[4];
  const float* Wv    = (const float*)d_in[5];
  const float* bv    = (const float*)d_in[6];
  const float* gamma = (const float*)d_in[7];
  float* out = (float*)d_out;

  char* ws = (char*)d_ws;
  unsigned short* Qt = (unsigned short*)(ws);                      // 1 MB
  unsigned short* Kt = (unsigned short*)(ws + (1u << 20));         // 1 MB
  unsigned char*  V8 = (unsigned char*)(ws + (2u << 20));          // 4 MB
  unsigned short* Wb = (unsigned short*)(ws + (6u << 20));         // 160 KB
  float* pmax  = (float*)(ws + (10u << 20));                       // 256 KB
  float* psum  = (float*)(ws + (10u << 20) + (1u << 18));          // 256 KB
  float* cbias = (float*)(ws + (10u << 20) + (2u << 18));          // 64 KB
  const size_t POUT_OFF = (11u << 20);
  float* pout = (float*)(ws + POUT_OFF);
  const size_t PART_BYTES = (size_t)NB * CC * NN * 4;              // 16 MB

  int nsplit = (ws_size >= POUT_OFF + 2 * PART_BYTES) ? 2 : 1;

  k_wcvt<<<dim3(80), 256, 0, stream>>>(Wq, Wk, Wv, Wb);
  k_proj<<<dim3(NN / 32, NB), 256, 0, stream>>>(x, Wb, bq, bk, bv, Qt, Kt, V8);
  k_rowstats_part<<<dim3(NN / 32, NB, MSPLIT), 256, 0, stream>>>(Qt, Kt, pmax, psum);
  k_statfin<<<dim3(NB * NN / 256), 256, 0, stream>>>(pmax, psum, cbias);
  k_attn_out<<<dim3(128 * nsplit), 512, 0, stream>>>(
      Qt, Kt, V8, cbias, pout, nsplit, NN / nsplit);
  k_comb<<<dim3(NN / 64, CC / 64, NB), 256, 0, stream>>>(pout, x, gamma, out, nsplit);
}